// Round 1
// baseline (3934.831 us; speedup 1.0000x reference)
//
#include <hip/hip_runtime.h>

// SNN constants: v_dec = v + 0.1*(i - v); i_dec = 0.8*i; spike if v_dec > 1.0
// v' = spike ? 0 : v_dec; i' = i_dec + input.

#define B_SZ 32
#define T_STEPS 32

// ---------------- Kernel A: conv1 (1->16, 5x5, 64->60) + LIF + 2x2 maxpool ----------------
// grid (32 b, 16 co), block 256. Stages the 64x64 input plane (16KB) in LDS.
__global__ __launch_bounds__(256) void k_conv1(
    const float* __restrict__ x_t,   // [B,64,64] for this step
    const float* __restrict__ w1,    // [16,1,5,5]
    const float* __restrict__ b1,    // [16]
    float* __restrict__ v0, float* __restrict__ i0,  // [B,16,60,60]
    float* __restrict__ zp1)         // [B,16,30,30] pooled spikes
{
    const int b = blockIdx.x, co = blockIdx.y;
    __shared__ float xs[4096];
    __shared__ float ws[25];
    const int t = threadIdx.x;

    const float4* xsrc = (const float4*)(x_t + b * 4096);
    float4* xdst = (float4*)xs;
    for (int i = t; i < 1024; i += 256) xdst[i] = xsrc[i];
    if (t < 25) ws[t] = w1[co * 25 + t];
    __syncthreads();

    const float bias = b1[co];

    for (int p = t; p < 900; p += 256) {
        const int py = p / 30, px = p % 30;
        const int y0 = 2 * py, x0 = 2 * px;

        float xr[6][6];
        #pragma unroll
        for (int r = 0; r < 6; ++r) {
            const float2* row = (const float2*)(xs + (y0 + r) * 64 + x0);
            float2 u0 = row[0], u1 = row[1], u2 = row[2];
            xr[r][0] = u0.x; xr[r][1] = u0.y; xr[r][2] = u1.x;
            xr[r][3] = u1.y; xr[r][4] = u2.x; xr[r][5] = u2.y;
        }

        float a00 = 0.f, a01 = 0.f, a10 = 0.f, a11 = 0.f;
        #pragma unroll
        for (int ky = 0; ky < 5; ++ky) {
            #pragma unroll
            for (int kx = 0; kx < 5; ++kx) {
                const float w = ws[ky * 5 + kx];
                a00 = fmaf(w, xr[ky][kx],       a00);
                a01 = fmaf(w, xr[ky][kx + 1],   a01);
                a10 = fmaf(w, xr[ky + 1][kx],   a10);
                a11 = fmaf(w, xr[ky + 1][kx + 1], a11);
            }
        }

        const int sbase = ((b * 16 + co) * 60 + y0) * 60 + x0;
        const float inp[4] = {a00 + bias, a01 + bias, a10 + bias, a11 + bias};
        const int idxs[4] = {sbase, sbase + 1, sbase + 60, sbase + 61};
        float zmax = 0.f;
        #pragma unroll
        for (int q = 0; q < 4; ++q) {
            const int si = idxs[q];
            const float v = v0[si], cur = i0[si];
            const float vd = v + 0.1f * (cur - v);
            const float id = 0.8f * cur;
            const float z = (vd - 1.0f > 0.0f) ? 1.0f : 0.0f;
            v0[si] = (z > 0.f) ? 0.f : vd;
            i0[si] = id + inp[q];
            zmax = fmaxf(zmax, z);
        }
        zp1[((b * 16 + co) * 30 + py) * 30 + px] = zmax;
    }
}

// ---------------- Kernel B: conv2 (16->32, 5x5, 30->26) *10 + LIF + pool ----------------
// grid (32 b, 32 co), block 192. Stages the full 16x30x30 input (57.6KB) in LDS.
__global__ __launch_bounds__(192) void k_conv2(
    const float* __restrict__ zp1,   // [B,16,30,30]
    const float* __restrict__ w2,    // [32,16,5,5]
    const float* __restrict__ b2,    // [32]
    float* __restrict__ v1, float* __restrict__ i1,  // [B,32,26,26]
    float* __restrict__ zp2T)        // [5408, 32] (k-major, batch minor)
{
    const int b = blockIdx.x, co = blockIdx.y;
    __shared__ float zs[14400];
    __shared__ float ws[400];
    const int t = threadIdx.x;

    const float4* src = (const float4*)(zp1 + b * 14400);
    float4* dst = (float4*)zs;
    for (int i = t; i < 3600; i += 192) dst[i] = src[i];
    for (int i = t; i < 400; i += 192) ws[i] = w2[co * 400 + i];
    __syncthreads();

    if (t >= 169) return;
    const float bias = b2[co];
    const int py = t / 13, px = t % 13;
    const int y0 = 2 * py, x0 = 2 * px;

    float a00 = 0.f, a01 = 0.f, a10 = 0.f, a11 = 0.f;
    for (int ci = 0; ci < 16; ++ci) {
        float xr[6][6];
        const int base = ci * 900 + y0 * 30 + x0;
        #pragma unroll
        for (int r = 0; r < 6; ++r) {
            const float2* row = (const float2*)(zs + base + r * 30);
            float2 u0 = row[0], u1 = row[1], u2 = row[2];
            xr[r][0] = u0.x; xr[r][1] = u0.y; xr[r][2] = u1.x;
            xr[r][3] = u1.y; xr[r][4] = u2.x; xr[r][5] = u2.y;
        }
        const float* wci = ws + ci * 25;
        #pragma unroll
        for (int ky = 0; ky < 5; ++ky) {
            #pragma unroll
            for (int kx = 0; kx < 5; ++kx) {
                const float w = wci[ky * 5 + kx];
                a00 = fmaf(w, xr[ky][kx],       a00);
                a01 = fmaf(w, xr[ky][kx + 1],   a01);
                a10 = fmaf(w, xr[ky + 1][kx],   a10);
                a11 = fmaf(w, xr[ky + 1][kx + 1], a11);
            }
        }
    }

    const float inp[4] = {10.f * (a00 + bias), 10.f * (a01 + bias),
                          10.f * (a10 + bias), 10.f * (a11 + bias)};
    const int sbase = ((b * 32 + co) * 26 + y0) * 26 + x0;
    const int idxs[4] = {sbase, sbase + 1, sbase + 26, sbase + 27};
    float zmax = 0.f;
    #pragma unroll
    for (int q = 0; q < 4; ++q) {
        const int si = idxs[q];
        const float v = v1[si], cur = i1[si];
        const float vd = v + 0.1f * (cur - v);
        const float id = 0.8f * cur;
        const float z = (vd - 1.0f > 0.0f) ? 1.0f : 0.0f;
        v1[si] = (z > 0.f) ? 0.f : vd;
        i1[si] = id + inp[q];
        zmax = fmaxf(zmax, z);
    }
    zp2T[(co * 169 + t) * 32 + b] = zmax;
}

// ---------------- Kernel C: FC 5408->500 + LIF ----------------
// grid 500 (one block per neuron), block 256 = 32 batches x 8 K-chunks.
__global__ __launch_bounds__(256) void k_fc(
    const float* __restrict__ zp2T,  // [5408,32]
    const float* __restrict__ fw,    // [500,5408]
    const float* __restrict__ fb,    // [500]
    float* __restrict__ v2, float* __restrict__ i2,  // [500,32]
    float* __restrict__ zr)          // [500,32] relu(spike)
{
    const int n = blockIdx.x;
    const int t = threadIdx.x;
    const int b = t & 31, kc = t >> 5;
    const float* __restrict__ wrow = fw + n * 5408;
    const int k0 = kc * 676;

    float acc = 0.f;
    #pragma unroll 4
    for (int j = 0; j < 676; ++j) {
        const int k = k0 + j;
        acc = fmaf(zp2T[k * 32 + b], wrow[k], acc);
    }

    __shared__ float red[256];
    red[t] = acc;
    __syncthreads();
    if (t < 32) {
        float s = 0.f;
        #pragma unroll
        for (int q = 0; q < 8; ++q) s += red[q * 32 + t];
        s += fb[n];
        const int si = n * 32 + t;
        const float v = v2[si], cur = i2[si];
        const float vd = v + 0.1f * (cur - v);
        const float id = 0.8f * cur;
        const float z = (vd - 1.0f > 0.0f) ? 1.0f : 0.0f;
        v2[si] = (z > 0.f) ? 0.f : vd;
        i2[si] = id + s;
        zr[si] = z;  // relu(0/1 spike) == spike
    }
}

// ---------------- Kernel D: readout 500->10, LI cell, emit v_out ----------------
// grid 10 (one block per class), block 256 = 32 batches x 8 N-chunks.
__global__ __launch_bounds__(256) void k_out(
    const float* __restrict__ zr,   // [500,32]
    const float* __restrict__ ow,   // [10,500]
    float* __restrict__ vo, float* __restrict__ io,  // [10,32]
    float* __restrict__ outp)       // d_out + t*320, layout [b][c]
{
    const int c = blockIdx.x;
    const int t = threadIdx.x;
    const int b = t & 31, nc = t >> 5;
    const float* __restrict__ wr = ow + c * 500;

    float acc = 0.f;
    for (int j = 0; j < 63; ++j) {
        const int n = nc * 63 + j;
        if (n < 500) acc = fmaf(zr[n * 32 + b], wr[n], acc);
    }

    __shared__ float red[256];
    red[t] = acc;
    __syncthreads();
    if (t < 32) {
        float dot = 0.f;
        #pragma unroll
        for (int q = 0; q < 8; ++q) dot += red[q * 32 + t];
        const int vi = c * 32 + t;
        const float v = vo[vi], cur = io[vi];
        const float vout = v + 0.1f * (cur - v);  // emitted BEFORE io update
        outp[t * 10 + c] = vout;
        vo[vi] = vout;
        io[vi] = 0.8f * cur + dot;
    }
}

extern "C" void kernel_launch(void* const* d_in, const int* in_sizes, int n_in,
                              void* d_out, int out_size, void* d_ws, size_t ws_size,
                              hipStream_t stream) {
    const float* x  = (const float*)d_in[0];  // [32,32,1,64,64]
    const float* w1 = (const float*)d_in[1];
    const float* b1 = (const float*)d_in[2];
    const float* w2 = (const float*)d_in[3];
    const float* b2 = (const float*)d_in[4];
    const float* fw = (const float*)d_in[5];
    const float* fb = (const float*)d_in[6];
    const float* ow = (const float*)d_in[7];
    float* out = (float*)d_out;
    float* ws = (float*)d_ws;

    size_t off = 0;
    float* v0  = ws + off; off += 1843200;  // 32*16*60*60
    float* i0_ = ws + off; off += 1843200;
    float* v1  = ws + off; off += 692224;   // 32*32*26*26
    float* i1_ = ws + off; off += 692224;
    float* v2  = ws + off; off += 16000;    // 500*32
    float* i2_ = ws + off; off += 16000;
    float* vo  = ws + off; off += 320;      // 10*32
    float* io_ = ws + off; off += 320;
    const size_t zero_count = off;          // states must start at 0
    float* zr   = ws + off; off += 16000;
    float* zp1  = ws + off; off += 460800;  // 32*16*30*30
    float* zp2T = ws + off; off += 173056;  // 5408*32

    hipMemsetAsync(d_ws, 0, zero_count * sizeof(float), stream);

    for (int t = 0; t < T_STEPS; ++t) {
        const float* xt = x + (size_t)t * B_SZ * 4096;
        k_conv1<<<dim3(B_SZ, 16), 256, 0, stream>>>(xt, w1, b1, v0, i0_, zp1);
        k_conv2<<<dim3(B_SZ, 32), 192, 0, stream>>>(zp1, w2, b2, v1, i1_, zp2T);
        k_fc<<<500, 256, 0, stream>>>(zp2T, fw, fb, v2, i2_, zr);
        k_out<<<10, 256, 0, stream>>>(zr, ow, vo, io_, out + (size_t)t * 320);
    }
}

// Round 2
// 2341.992 us; speedup vs baseline: 1.6801x; 1.6801x over previous
//
#include <hip/hip_runtime.h>

// SNN constants: v_dec = v + 0.1*(i - v); i_dec = 0.8*i; spike if v_dec > 1.0
// v' = spike ? 0 : v_dec; i' = i_dec + input.

#define B_SZ 32
#define T_STEPS 32

// ---------------- Kernel A: conv1 (1->16, 5x5, 64->60) + LIF + 2x2 maxpool ----------------
// grid (32 b, 16 co), block 256. Stages the 64x64 input plane (16KB) in LDS.
__global__ __launch_bounds__(256) void k_conv1(
    const float* __restrict__ x_t,   // [B,64,64] for this step
    const float* __restrict__ w1,    // [16,1,5,5]
    const float* __restrict__ b1,    // [16]
    float* __restrict__ v0, float* __restrict__ i0,  // [B,16,60,60]
    float* __restrict__ zp1)         // [B,16,30,30] pooled spikes
{
    const int b = blockIdx.x, co = blockIdx.y;
    __shared__ float xs[4096];
    __shared__ float ws[25];
    const int t = threadIdx.x;

    const float4* xsrc = (const float4*)(x_t + b * 4096);
    float4* xdst = (float4*)xs;
    for (int i = t; i < 1024; i += 256) xdst[i] = xsrc[i];
    if (t < 25) ws[t] = w1[co * 25 + t];
    __syncthreads();

    const float bias = b1[co];

    for (int p = t; p < 900; p += 256) {
        const int py = p / 30, px = p % 30;
        const int y0 = 2 * py, x0 = 2 * px;

        float xr[6][6];
        #pragma unroll
        for (int r = 0; r < 6; ++r) {
            const float2* row = (const float2*)(xs + (y0 + r) * 64 + x0);
            float2 u0 = row[0], u1 = row[1], u2 = row[2];
            xr[r][0] = u0.x; xr[r][1] = u0.y; xr[r][2] = u1.x;
            xr[r][3] = u1.y; xr[r][4] = u2.x; xr[r][5] = u2.y;
        }

        float a00 = 0.f, a01 = 0.f, a10 = 0.f, a11 = 0.f;
        #pragma unroll
        for (int ky = 0; ky < 5; ++ky) {
            #pragma unroll
            for (int kx = 0; kx < 5; ++kx) {
                const float w = ws[ky * 5 + kx];
                a00 = fmaf(w, xr[ky][kx],       a00);
                a01 = fmaf(w, xr[ky][kx + 1],   a01);
                a10 = fmaf(w, xr[ky + 1][kx],   a10);
                a11 = fmaf(w, xr[ky + 1][kx + 1], a11);
            }
        }

        const int sbase = ((b * 16 + co) * 60 + y0) * 60 + x0;
        const float inp[4] = {a00 + bias, a01 + bias, a10 + bias, a11 + bias};
        const int idxs[4] = {sbase, sbase + 1, sbase + 60, sbase + 61};
        float zmax = 0.f;
        #pragma unroll
        for (int q = 0; q < 4; ++q) {
            const int si = idxs[q];
            const float v = v0[si], cur = i0[si];
            const float vd = v + 0.1f * (cur - v);
            const float id = 0.8f * cur;
            const float z = (vd - 1.0f > 0.0f) ? 1.0f : 0.0f;
            v0[si] = (z > 0.f) ? 0.f : vd;
            i0[si] = id + inp[q];
            zmax = fmaxf(zmax, z);
        }
        zp1[((b * 16 + co) * 30 + py) * 30 + px] = zmax;
    }
}

// ---------------- Kernel B: conv2 (16->32, 5x5, 30->26) *10 + LIF + pool ----------------
// grid (32 b, 32 co), block 192. Stages the full 16x30x30 input (57.6KB) in LDS.
__global__ __launch_bounds__(192) void k_conv2(
    const float* __restrict__ zp1,   // [B,16,30,30]
    const float* __restrict__ w2,    // [32,16,5,5]
    const float* __restrict__ b2,    // [32]
    float* __restrict__ v1, float* __restrict__ i1,  // [B,32,26,26]
    float* __restrict__ zp2T)        // [5408, 32] (k-major, batch minor)
{
    const int b = blockIdx.x, co = blockIdx.y;
    __shared__ float zs[14400];
    __shared__ float ws[400];
    const int t = threadIdx.x;

    const float4* src = (const float4*)(zp1 + b * 14400);
    float4* dst = (float4*)zs;
    for (int i = t; i < 3600; i += 192) dst[i] = src[i];
    for (int i = t; i < 400; i += 192) ws[i] = w2[co * 400 + i];
    __syncthreads();

    if (t >= 169) return;
    const float bias = b2[co];
    const int py = t / 13, px = t % 13;
    const int y0 = 2 * py, x0 = 2 * px;

    float a00 = 0.f, a01 = 0.f, a10 = 0.f, a11 = 0.f;
    for (int ci = 0; ci < 16; ++ci) {
        float xr[6][6];
        const int base = ci * 900 + y0 * 30 + x0;
        #pragma unroll
        for (int r = 0; r < 6; ++r) {
            const float2* row = (const float2*)(zs + base + r * 30);
            float2 u0 = row[0], u1 = row[1], u2 = row[2];
            xr[r][0] = u0.x; xr[r][1] = u0.y; xr[r][2] = u1.x;
            xr[r][3] = u1.y; xr[r][4] = u2.x; xr[r][5] = u2.y;
        }
        const float* wci = ws + ci * 25;
        #pragma unroll
        for (int ky = 0; ky < 5; ++ky) {
            #pragma unroll
            for (int kx = 0; kx < 5; ++kx) {
                const float w = wci[ky * 5 + kx];
                a00 = fmaf(w, xr[ky][kx],       a00);
                a01 = fmaf(w, xr[ky][kx + 1],   a01);
                a10 = fmaf(w, xr[ky + 1][kx],   a10);
                a11 = fmaf(w, xr[ky + 1][kx + 1], a11);
            }
        }
    }

    const float inp[4] = {10.f * (a00 + bias), 10.f * (a01 + bias),
                          10.f * (a10 + bias), 10.f * (a11 + bias)};
    const int sbase = ((b * 32 + co) * 26 + y0) * 26 + x0;
    const int idxs[4] = {sbase, sbase + 1, sbase + 26, sbase + 27};
    float zmax = 0.f;
    #pragma unroll
    for (int q = 0; q < 4; ++q) {
        const int si = idxs[q];
        const float v = v1[si], cur = i1[si];
        const float vd = v + 0.1f * (cur - v);
        const float id = 0.8f * cur;
        const float z = (vd - 1.0f > 0.0f) ? 1.0f : 0.0f;
        v1[si] = (z > 0.f) ? 0.f : vd;
        i1[si] = id + inp[q];
        zmax = fmaxf(zmax, z);
    }
    zp2T[(co * 169 + t) * 32 + b] = zmax;
}

// ---------------- Kernel C1: FC partial dot-products ----------------
// grid (500 n, 8 kchunk), block 64 (one wave). Lane = batch(32) x half(2).
// Each half covers 338 K. 4000 waves of TLP; 4 independent accumulators.
__global__ __launch_bounds__(64) void k_fc1(
    const float* __restrict__ zp2T,  // [5408,32]
    const float* __restrict__ fw,    // [500,5408]
    float* __restrict__ part)        // [8][500][32]
{
    const int n = blockIdx.x, c = blockIdx.y;
    const int l = threadIdx.x;
    const int b = l & 31, h = l >> 5;
    const int k0 = c * 676 + h * 338;

    const float* __restrict__ wp = fw + n * 5408 + k0;
    const float* __restrict__ zp = zp2T + k0 * 32 + b;

    float a0 = 0.f, a1 = 0.f, a2 = 0.f, a3 = 0.f;
    for (int j = 0; j < 84; ++j) {
        a0 = fmaf(wp[0], zp[0],  a0);
        a1 = fmaf(wp[1], zp[32], a1);
        a2 = fmaf(wp[2], zp[64], a2);
        a3 = fmaf(wp[3], zp[96], a3);
        wp += 4; zp += 128;
    }
    // remainder: 338 - 336 = 2
    a0 = fmaf(wp[0], zp[0],  a0);
    a1 = fmaf(wp[1], zp[32], a1);
    float a = (a0 + a1) + (a2 + a3);

    // combine halves: lane l gets lane l+32's value
    a += __shfl_down(a, 32);
    if (l < 32) part[(c * 500 + n) * 32 + l] = a;
}

// ---------------- Kernel C2: reduce partials + bias + LIF ----------------
// grid 63, block 256 (16128 threads for 16000 outputs).
__global__ __launch_bounds__(256) void k_fc2(
    const float* __restrict__ part,  // [8][500][32]
    const float* __restrict__ fb,    // [500]
    float* __restrict__ v2, float* __restrict__ i2,  // [500*32], idx = n*32+b
    float* __restrict__ zrB)         // [32,500] spikes, batch-major
{
    const int idx = blockIdx.x * 256 + threadIdx.x;
    if (idx >= 16000) return;
    const int n = idx >> 5, b = idx & 31;

    float s = 0.f;
    #pragma unroll
    for (int p = 0; p < 8; ++p) s += part[p * 16000 + idx];
    s += fb[n];

    const float v = v2[idx], cur = i2[idx];
    const float vd = v + 0.1f * (cur - v);
    const float id = 0.8f * cur;
    const float z = (vd - 1.0f > 0.0f) ? 1.0f : 0.0f;
    v2[idx] = (z > 0.f) ? 0.f : vd;
    i2[idx] = id + s;
    zrB[b * 500 + n] = z;  // relu(0/1 spike) == spike
}

// ---------------- Kernel D: readout 500->10, LI cell, emit v_out ----------------
// grid (10 c, 32 b), block 64 (one wave). Lanes stride over the 500 neurons.
__global__ __launch_bounds__(64) void k_out(
    const float* __restrict__ zrB,  // [32,500]
    const float* __restrict__ ow,   // [10,500]
    float* __restrict__ vo, float* __restrict__ io,  // [10*32], idx = c*32+b
    float* __restrict__ outp)       // d_out + t*320, layout [b][c]
{
    const int c = blockIdx.x, b = blockIdx.y;
    const int l = threadIdx.x;
    const float* __restrict__ wr = ow + c * 500;
    const float* __restrict__ zb = zrB + b * 500;

    float a = 0.f;
    for (int n = l; n < 500; n += 64) a = fmaf(zb[n], wr[n], a);
    #pragma unroll
    for (int off = 32; off > 0; off >>= 1) a += __shfl_down(a, off);

    if (l == 0) {
        const int vi = c * 32 + b;
        const float v = vo[vi], cur = io[vi];
        const float vout = v + 0.1f * (cur - v);  // emitted BEFORE io update
        outp[b * 10 + c] = vout;
        vo[vi] = vout;
        io[vi] = 0.8f * cur + a;
    }
}

extern "C" void kernel_launch(void* const* d_in, const int* in_sizes, int n_in,
                              void* d_out, int out_size, void* d_ws, size_t ws_size,
                              hipStream_t stream) {
    const float* x  = (const float*)d_in[0];  // [32,32,1,64,64]
    const float* w1 = (const float*)d_in[1];
    const float* b1 = (const float*)d_in[2];
    const float* w2 = (const float*)d_in[3];
    const float* b2 = (const float*)d_in[4];
    const float* fw = (const float*)d_in[5];
    const float* fb = (const float*)d_in[6];
    const float* ow = (const float*)d_in[7];
    float* out = (float*)d_out;
    float* ws = (float*)d_ws;

    size_t off = 0;
    float* v0  = ws + off; off += 1843200;  // 32*16*60*60
    float* i0_ = ws + off; off += 1843200;
    float* v1  = ws + off; off += 692224;   // 32*32*26*26
    float* i1_ = ws + off; off += 692224;
    float* v2  = ws + off; off += 16000;    // 500*32
    float* i2_ = ws + off; off += 16000;
    float* vo  = ws + off; off += 320;      // 10*32
    float* io_ = ws + off; off += 320;
    const size_t zero_count = off;          // states must start at 0
    float* zrB  = ws + off; off += 16000;   // [32,500]
    float* zp1  = ws + off; off += 460800;  // 32*16*30*30
    float* zp2T = ws + off; off += 173056;  // 5408*32
    float* part = ws + off; off += 128000;  // [8][500][32]

    hipMemsetAsync(d_ws, 0, zero_count * sizeof(float), stream);

    for (int t = 0; t < T_STEPS; ++t) {
        const float* xt = x + (size_t)t * B_SZ * 4096;
        k_conv1<<<dim3(B_SZ, 16), 256, 0, stream>>>(xt, w1, b1, v0, i0_, zp1);
        k_conv2<<<dim3(B_SZ, 32), 192, 0, stream>>>(zp1, w2, b2, v1, i1_, zp2T);
        k_fc1<<<dim3(500, 8), 64, 0, stream>>>(zp2T, fw, part);
        k_fc2<<<63, 256, 0, stream>>>(part, fb, v2, i2_, zrB);
        k_out<<<dim3(10, B_SZ), 64, 0, stream>>>(zrB, ow, vo, io_, out + (size_t)t * 320);
    }
}

// Round 3
// 1962.997 us; speedup vs baseline: 2.0045x; 1.1931x over previous
//
#include <hip/hip_runtime.h>

// SNN constants: v_dec = v + 0.1*(i - v); i_dec = 0.8*i; spike if v_dec > 1.0
// v' = spike ? 0 : v_dec; i' = i_dec + input.

#define B_SZ 32
#define T_STEPS 32

// ---------------- Kernel A: conv1 (1->16, 5x5, 64->60) + LIF + 2x2 maxpool ----------------
// grid (32 b, 16 co), block 256. Stages the 64x64 input plane (16KB) in LDS.
// Pooled spikes written BATCH-MINOR: zp1T[co][py][px][b].
__global__ __launch_bounds__(256) void k_conv1(
    const float* __restrict__ x_t,   // [B,64,64] for this step
    const float* __restrict__ w1,    // [16,1,5,5]
    const float* __restrict__ b1,    // [16]
    float* __restrict__ v0, float* __restrict__ i0,  // [B,16,60,60]
    float* __restrict__ zp1T)        // [16,30,30,32]
{
    const int b = blockIdx.x, co = blockIdx.y;
    __shared__ float xs[4096];
    __shared__ float ws[25];
    const int t = threadIdx.x;

    const float4* xsrc = (const float4*)(x_t + b * 4096);
    float4* xdst = (float4*)xs;
    for (int i = t; i < 1024; i += 256) xdst[i] = xsrc[i];
    if (t < 25) ws[t] = w1[co * 25 + t];
    __syncthreads();

    const float bias = b1[co];

    for (int p = t; p < 900; p += 256) {
        const int py = p / 30, px = p % 30;
        const int y0 = 2 * py, x0 = 2 * px;

        float xr[6][6];
        #pragma unroll
        for (int r = 0; r < 6; ++r) {
            const float2* row = (const float2*)(xs + (y0 + r) * 64 + x0);
            float2 u0 = row[0], u1 = row[1], u2 = row[2];
            xr[r][0] = u0.x; xr[r][1] = u0.y; xr[r][2] = u1.x;
            xr[r][3] = u1.y; xr[r][4] = u2.x; xr[r][5] = u2.y;
        }

        float a00 = 0.f, a01 = 0.f, a10 = 0.f, a11 = 0.f;
        #pragma unroll
        for (int ky = 0; ky < 5; ++ky) {
            #pragma unroll
            for (int kx = 0; kx < 5; ++kx) {
                const float w = ws[ky * 5 + kx];
                a00 = fmaf(w, xr[ky][kx],       a00);
                a01 = fmaf(w, xr[ky][kx + 1],   a01);
                a10 = fmaf(w, xr[ky + 1][kx],   a10);
                a11 = fmaf(w, xr[ky + 1][kx + 1], a11);
            }
        }

        const int sbase = ((b * 16 + co) * 60 + y0) * 60 + x0;
        const float inp[4] = {a00 + bias, a01 + bias, a10 + bias, a11 + bias};
        const int idxs[4] = {sbase, sbase + 1, sbase + 60, sbase + 61};
        float zmax = 0.f;
        #pragma unroll
        for (int q = 0; q < 4; ++q) {
            const int si = idxs[q];
            const float v = v0[si], cur = i0[si];
            const float vd = v + 0.1f * (cur - v);
            const float id = 0.8f * cur;
            const float z = (vd - 1.0f > 0.0f) ? 1.0f : 0.0f;
            v0[si] = (z > 0.f) ? 0.f : vd;
            i0[si] = id + inp[q];
            zmax = fmaxf(zmax, z);
        }
        zp1T[((co * 30 + py) * 30 + px) * 32 + b] = zmax;
    }
}

// ---------------- Kernel B: conv2 (16->32, 5x5, 30->26) *10 + LIF + pool ----------------
// Batch-minor everywhere. grid (169 pos, 2 co-halves), block 256 = 32b x 8 slots.
// Each thread: 2 co x 2x2 points, input window in registers, weights in LDS.
__global__ __launch_bounds__(256) void k_conv2(
    const float* __restrict__ zp1T,  // [16,30,30,32]
    const float* __restrict__ w2,    // [32,16,5,5]
    const float* __restrict__ b2,    // [32]
    float* __restrict__ v1, float* __restrict__ i1,  // [32,26,26,32] batch-minor
    float* __restrict__ zp2T)        // [5408, 32]
{
    const int pos = blockIdx.x;            // 0..168
    const int cob = blockIdx.y * 16;       // 0 or 16
    const int py = pos / 13, px = pos % 13;
    const int y0 = 2 * py, x0 = 2 * px;
    const int t = threadIdx.x;
    const int b = t & 31, slot = t >> 5;   // 8 slots

    // weights padded to 28-float rows for aligned b128 reads: [16co][16ci][28]
    __shared__ float ws[7168];
    __shared__ float bs[16];

    for (int i = t; i < 6400; i += 256) {
        const int co_l = i / 400;
        const int rest = i - co_l * 400;
        const int ci = rest / 25;
        const int j = rest - ci * 25;
        ws[(co_l * 16 + ci) * 28 + j] = w2[cob * 400 + i];
    }
    if (t < 16) bs[t] = b2[cob + t];
    __syncthreads();

    float accA[4] = {0.f, 0.f, 0.f, 0.f};
    float accB[4] = {0.f, 0.f, 0.f, 0.f};

    for (int ci = 0; ci < 16; ++ci) {
        float xr[6][6];
        const float* __restrict__ ip = zp1T + ((ci * 30 + y0) * 30 + x0) * 32 + b;
        #pragma unroll
        for (int r = 0; r < 6; ++r) {
            #pragma unroll
            for (int c = 0; c < 6; ++c)
                xr[r][c] = ip[(r * 30 + c) * 32];
        }
        const float* __restrict__ wA = ws + ((slot)     * 16 + ci) * 28;
        const float* __restrict__ wB = ws + ((slot + 8) * 16 + ci) * 28;
        #pragma unroll
        for (int ky = 0; ky < 5; ++ky) {
            #pragma unroll
            for (int kx = 0; kx < 5; ++kx) {
                const float a = wA[ky * 5 + kx];
                const float c = wB[ky * 5 + kx];
                accA[0] = fmaf(a, xr[ky][kx],         accA[0]);
                accA[1] = fmaf(a, xr[ky][kx + 1],     accA[1]);
                accA[2] = fmaf(a, xr[ky + 1][kx],     accA[2]);
                accA[3] = fmaf(a, xr[ky + 1][kx + 1], accA[3]);
                accB[0] = fmaf(c, xr[ky][kx],         accB[0]);
                accB[1] = fmaf(c, xr[ky][kx + 1],     accB[1]);
                accB[2] = fmaf(c, xr[ky + 1][kx],     accB[2]);
                accB[3] = fmaf(c, xr[ky + 1][kx + 1], accB[3]);
            }
        }
    }

    #pragma unroll
    for (int half = 0; half < 2; ++half) {
        const int co = cob + slot + half * 8;
        const float* acc = half ? accB : accA;
        const float bias = bs[slot + half * 8];
        float zmax = 0.f;
        #pragma unroll
        for (int q = 0; q < 4; ++q) {
            const int y = y0 + (q >> 1), x = x0 + (q & 1);
            const int si = ((co * 26 + y) * 26 + x) * 32 + b;
            const float inp = 10.f * (acc[q] + bias);
            const float v = v1[si], cur = i1[si];
            const float vd = v + 0.1f * (cur - v);
            const float id = 0.8f * cur;
            const float z = (vd - 1.0f > 0.0f) ? 1.0f : 0.0f;
            v1[si] = (z > 0.f) ? 0.f : vd;
            i1[si] = id + inp;
            zmax = fmaxf(zmax, z);
        }
        zp2T[(co * 169 + pos) * 32 + b] = zmax;
    }
}

// ---------------- Kernel C1: FC partial dot-products ----------------
// grid (500 n, 8 kchunk), block 64 (one wave). Lane = batch(32) x half(2).
__global__ __launch_bounds__(64) void k_fc1(
    const float* __restrict__ zp2T,  // [5408,32]
    const float* __restrict__ fw,    // [500,5408]
    float* __restrict__ part)        // [8][500][32]
{
    const int n = blockIdx.x, c = blockIdx.y;
    const int l = threadIdx.x;
    const int b = l & 31, h = l >> 5;
    const int k0 = c * 676 + h * 338;

    const float* __restrict__ wp = fw + n * 5408 + k0;
    const float* __restrict__ zp = zp2T + k0 * 32 + b;

    float a0 = 0.f, a1 = 0.f, a2 = 0.f, a3 = 0.f;
    for (int j = 0; j < 84; ++j) {
        a0 = fmaf(wp[0], zp[0],  a0);
        a1 = fmaf(wp[1], zp[32], a1);
        a2 = fmaf(wp[2], zp[64], a2);
        a3 = fmaf(wp[3], zp[96], a3);
        wp += 4; zp += 128;
    }
    a0 = fmaf(wp[0], zp[0],  a0);
    a1 = fmaf(wp[1], zp[32], a1);
    float a = (a0 + a1) + (a2 + a3);

    a += __shfl_down(a, 32);
    if (l < 32) part[(c * 500 + n) * 32 + l] = a;
}

// ---------------- Kernel C2: reduce partials + bias + LIF ----------------
__global__ __launch_bounds__(256) void k_fc2(
    const float* __restrict__ part,  // [8][500][32]
    const float* __restrict__ fb,    // [500]
    float* __restrict__ v2, float* __restrict__ i2,  // [500*32], idx = n*32+b
    float* __restrict__ zrB)         // [32,500] spikes, batch-major
{
    const int idx = blockIdx.x * 256 + threadIdx.x;
    if (idx >= 16000) return;
    const int n = idx >> 5, b = idx & 31;

    float s = 0.f;
    #pragma unroll
    for (int p = 0; p < 8; ++p) s += part[p * 16000 + idx];
    s += fb[n];

    const float v = v2[idx], cur = i2[idx];
    const float vd = v + 0.1f * (cur - v);
    const float id = 0.8f * cur;
    const float z = (vd - 1.0f > 0.0f) ? 1.0f : 0.0f;
    v2[idx] = (z > 0.f) ? 0.f : vd;
    i2[idx] = id + s;
    zrB[b * 500 + n] = z;
}

// ---------------- Kernel D: readout 500->10, LI cell, emit v_out ----------------
__global__ __launch_bounds__(64) void k_out(
    const float* __restrict__ zrB,  // [32,500]
    const float* __restrict__ ow,   // [10,500]
    float* __restrict__ vo, float* __restrict__ io,  // [10*32], idx = c*32+b
    float* __restrict__ outp)       // d_out + t*320, layout [b][c]
{
    const int c = blockIdx.x, b = blockIdx.y;
    const int l = threadIdx.x;
    const float* __restrict__ wr = ow + c * 500;
    const float* __restrict__ zb = zrB + b * 500;

    float a = 0.f;
    for (int n = l; n < 500; n += 64) a = fmaf(zb[n], wr[n], a);
    #pragma unroll
    for (int off = 32; off > 0; off >>= 1) a += __shfl_down(a, off);

    if (l == 0) {
        const int vi = c * 32 + b;
        const float v = vo[vi], cur = io[vi];
        const float vout = v + 0.1f * (cur - v);  // emitted BEFORE io update
        outp[b * 10 + c] = vout;
        vo[vi] = vout;
        io[vi] = 0.8f * cur + a;
    }
}

extern "C" void kernel_launch(void* const* d_in, const int* in_sizes, int n_in,
                              void* d_out, int out_size, void* d_ws, size_t ws_size,
                              hipStream_t stream) {
    const float* x  = (const float*)d_in[0];  // [32,32,1,64,64]
    const float* w1 = (const float*)d_in[1];
    const float* b1 = (const float*)d_in[2];
    const float* w2 = (const float*)d_in[3];
    const float* b2 = (const float*)d_in[4];
    const float* fw = (const float*)d_in[5];
    const float* fb = (const float*)d_in[6];
    const float* ow = (const float*)d_in[7];
    float* out = (float*)d_out;
    float* ws = (float*)d_ws;

    size_t off = 0;
    float* v0  = ws + off; off += 1843200;  // 32*16*60*60
    float* i0_ = ws + off; off += 1843200;
    float* v1  = ws + off; off += 692224;   // 32*26*26*32 batch-minor
    float* i1_ = ws + off; off += 692224;
    float* v2  = ws + off; off += 16000;    // 500*32
    float* i2_ = ws + off; off += 16000;
    float* vo  = ws + off; off += 320;      // 10*32
    float* io_ = ws + off; off += 320;
    const size_t zero_count = off;          // states must start at 0
    float* zrB  = ws + off; off += 16000;   // [32,500]
    float* zp1T = ws + off; off += 460800;  // [16,30,30,32]
    float* zp2T = ws + off; off += 173056;  // [5408,32]
    float* part = ws + off; off += 128000;  // [8][500][32]

    hipMemsetAsync(d_ws, 0, zero_count * sizeof(float), stream);

    for (int t = 0; t < T_STEPS; ++t) {
        const float* xt = x + (size_t)t * B_SZ * 4096;
        k_conv1<<<dim3(B_SZ, 16), 256, 0, stream>>>(xt, w1, b1, v0, i0_, zp1T);
        k_conv2<<<dim3(169, 2), 256, 0, stream>>>(zp1T, w2, b2, v1, i1_, zp2T);
        k_fc1<<<dim3(500, 8), 64, 0, stream>>>(zp2T, fw, part);
        k_fc2<<<63, 256, 0, stream>>>(part, fb, v2, i2_, zrB);
        k_out<<<dim3(10, B_SZ), 64, 0, stream>>>(zrB, ow, vo, io_, out + (size_t)t * 320);
    }
}

// Round 4
// 1213.033 us; speedup vs baseline: 3.2438x; 1.6183x over previous
//
#include <hip/hip_runtime.h>

// SNN: v_dec = v + 0.1*(i - v); i_dec = 0.8*i; spike if v_dec > 1.0
// v' = spike ? 0 : v_dec; i' = i_dec + input.
// Whole-sequence kernels: LIF state lives in registers across the t-loop.

#define T_STEPS 32

// ---------------- K0: transpose x [t][b][64][64] -> xT [t][y][x][b] ----------------
__global__ __launch_bounds__(256) void k_tr(
    const float* __restrict__ x, float* __restrict__ xT)
{
    const int y = blockIdx.x, t = blockIdx.y;
    const int tid = threadIdx.x;
    __shared__ float tile[32][65];

    // load row y of all 32 batches, coalesced in x
    const int lx = tid & 63, bg = tid >> 6;  // 4 b per pass
    #pragma unroll
    for (int p = 0; p < 8; ++p) {
        const int b = bg + p * 4;
        tile[b][lx] = x[((size_t)(t * 32 + b) * 64 + y) * 64 + lx];
    }
    __syncthreads();
    // write batch-minor, coalesced in b
    const int wb = tid & 31, xg = tid >> 5;  // 8 x per pass
    #pragma unroll
    for (int p = 0; p < 8; ++p) {
        const int xx = xg + p * 8;
        xT[((size_t)(t * 64 + y) * 64 + xx) * 32 + wb] = tile[wb][xx];
    }
}

// ---------------- K1: conv1 (1->16) + LIF + pool, ALL timesteps ----------------
// grid 900 (pooled pos), block 256 = 32 b x 8 slots (2 co per slot).
__global__ __launch_bounds__(256) void k1_conv1(
    const float* __restrict__ xT,    // [32t,64,64,32b]
    const float* __restrict__ w1,    // [16,1,5,5]
    const float* __restrict__ b1,    // [16]
    float* __restrict__ zp1a)        // [32t][16,30,30,32b]
{
    const int pos = blockIdx.x;
    const int py = pos / 30, px = pos % 30;
    const int y0 = 2 * py, x0 = 2 * px;
    const int tid = threadIdx.x;
    const int b = tid & 31, slot = tid >> 5;

    __shared__ float ws[400];
    __shared__ float win[1152];      // [6*6][32b]
    for (int i = tid; i < 400; i += 256) ws[i] = w1[i];
    const float bias0 = b1[slot], bias1 = b1[slot + 8];

    float v[2][4] = {{0.f,0.f,0.f,0.f},{0.f,0.f,0.f,0.f}};
    float cu[2][4] = {{0.f,0.f,0.f,0.f},{0.f,0.f,0.f,0.f}};

    for (int t = 0; t < T_STEPS; ++t) {
        __syncthreads();  // ws ready (t=0) / win consumers done (t>0)
        for (int i = tid; i < 1152; i += 256) {
            const int rc = i >> 5, bb = i & 31;
            const int r = rc / 6, c = rc - 6 * r;
            win[i] = xT[((size_t)(t * 64 + y0 + r) * 64 + (x0 + c)) * 32 + bb];
        }
        __syncthreads();

        float xr[6][6];
        #pragma unroll
        for (int r = 0; r < 6; ++r)
            #pragma unroll
            for (int c = 0; c < 6; ++c)
                xr[r][c] = win[(r * 6 + c) * 32 + b];

        #pragma unroll
        for (int half = 0; half < 2; ++half) {
            const int co = slot + 8 * half;
            const float* wc = ws + co * 25;
            float a00 = 0.f, a01 = 0.f, a10 = 0.f, a11 = 0.f;
            #pragma unroll
            for (int ky = 0; ky < 5; ++ky) {
                #pragma unroll
                for (int kx = 0; kx < 5; ++kx) {
                    const float w = wc[ky * 5 + kx];
                    a00 = fmaf(w, xr[ky][kx],         a00);
                    a01 = fmaf(w, xr[ky][kx + 1],     a01);
                    a10 = fmaf(w, xr[ky + 1][kx],     a10);
                    a11 = fmaf(w, xr[ky + 1][kx + 1], a11);
                }
            }
            const float bias = half ? bias1 : bias0;
            const float inp[4] = {a00 + bias, a01 + bias, a10 + bias, a11 + bias};
            float zmax = 0.f;
            #pragma unroll
            for (int q = 0; q < 4; ++q) {
                const float vv = v[half][q], cur = cu[half][q];
                const float vd = vv + 0.1f * (cur - vv);
                const float id = 0.8f * cur;
                const float z = (vd - 1.0f > 0.0f) ? 1.0f : 0.0f;
                v[half][q] = (z > 0.f) ? 0.f : vd;
                cu[half][q] = id + inp[q];
                zmax = fmaxf(zmax, z);
            }
            zp1a[(size_t)t * 460800 + ((co * 30 + py) * 30 + px) * 32 + b] = zmax;
        }
    }
}

// ---------------- K2: conv2 (16->32)*10 + LIF + pool, ALL timesteps ----------------
// grid (169 pos, 2 co-halves), block 256 = 32 b x 8 slots (2 co per slot).
__global__ __launch_bounds__(256) void k2_conv2(
    const float* __restrict__ zp1a,  // [32t][16,30,30,32b]
    const float* __restrict__ w2,    // [32,16,5,5]
    const float* __restrict__ b2,    // [32]
    float* __restrict__ zp2a)        // [32t][5408,32b]
{
    const int pos = blockIdx.x;
    const int cob = blockIdx.y * 16;
    const int py = pos / 13, px = pos % 13;
    const int y0 = 2 * py, x0 = 2 * px;
    const int tid = threadIdx.x;
    const int b = tid & 31, slot = tid >> 5;

    __shared__ float ws[7168];  // [16co][16ci][28 padded]
    __shared__ float bs[16];
    for (int i = tid; i < 6400; i += 256) {
        const int co_l = i / 400;
        const int rest = i - co_l * 400;
        const int ci = rest / 25;
        const int j = rest - ci * 25;
        ws[(co_l * 16 + ci) * 28 + j] = w2[cob * 400 + i];
    }
    if (tid < 16) bs[tid] = b2[cob + tid];
    __syncthreads();

    float v[2][4] = {{0.f,0.f,0.f,0.f},{0.f,0.f,0.f,0.f}};
    float cu[2][4] = {{0.f,0.f,0.f,0.f},{0.f,0.f,0.f,0.f}};

    for (int t = 0; t < T_STEPS; ++t) {
        const float* __restrict__ zt = zp1a + (size_t)t * 460800;
        float accA[4] = {0.f, 0.f, 0.f, 0.f};
        float accB[4] = {0.f, 0.f, 0.f, 0.f};

        for (int ci = 0; ci < 16; ++ci) {
            float xr[6][6];
            const float* __restrict__ ip = zt + ((ci * 30 + y0) * 30 + x0) * 32 + b;
            #pragma unroll
            for (int r = 0; r < 6; ++r)
                #pragma unroll
                for (int c = 0; c < 6; ++c)
                    xr[r][c] = ip[(r * 30 + c) * 32];

            const float* __restrict__ wA = ws + ((slot)     * 16 + ci) * 28;
            const float* __restrict__ wB = ws + ((slot + 8) * 16 + ci) * 28;
            #pragma unroll
            for (int ky = 0; ky < 5; ++ky) {
                #pragma unroll
                for (int kx = 0; kx < 5; ++kx) {
                    const float a = wA[ky * 5 + kx];
                    const float c = wB[ky * 5 + kx];
                    accA[0] = fmaf(a, xr[ky][kx],         accA[0]);
                    accA[1] = fmaf(a, xr[ky][kx + 1],     accA[1]);
                    accA[2] = fmaf(a, xr[ky + 1][kx],     accA[2]);
                    accA[3] = fmaf(a, xr[ky + 1][kx + 1], accA[3]);
                    accB[0] = fmaf(c, xr[ky][kx],         accB[0]);
                    accB[1] = fmaf(c, xr[ky][kx + 1],     accB[1]);
                    accB[2] = fmaf(c, xr[ky + 1][kx],     accB[2]);
                    accB[3] = fmaf(c, xr[ky + 1][kx + 1], accB[3]);
                }
            }
        }

        #pragma unroll
        for (int half = 0; half < 2; ++half) {
            const int co = cob + slot + half * 8;
            const float* acc = half ? accB : accA;
            const float bias = bs[slot + half * 8];
            float zmax = 0.f;
            #pragma unroll
            for (int q = 0; q < 4; ++q) {
                const float inp = 10.f * (acc[q] + bias);
                const float vv = v[half][q], cur = cu[half][q];
                const float vd = vv + 0.1f * (cur - vv);
                const float id = 0.8f * cur;
                const float z = (vd - 1.0f > 0.0f) ? 1.0f : 0.0f;
                v[half][q] = (z > 0.f) ? 0.f : vd;
                cu[half][q] = id + inp;
                zmax = fmaxf(zmax, z);
            }
            zp2a[(size_t)t * 173056 + (co * 169 + pos) * 32 + b] = zmax;
        }
    }
}

// ---------------- K3a: FC partial dots, ALL timesteps ----------------
// grid (500 n, 8 kchunk, 32 t), block 64. Lane = batch(32) x half(2).
__global__ __launch_bounds__(64) void k3_fc(
    const float* __restrict__ zp2a,  // [32t][5408,32]
    const float* __restrict__ fw,    // [500,5408]
    float* __restrict__ part)        // [32t][8][500][32]
{
    const int n = blockIdx.x, c = blockIdx.y, t = blockIdx.z;
    const int l = threadIdx.x;
    const int b = l & 31, h = l >> 5;
    const int k0 = c * 676 + h * 338;

    const float* __restrict__ wp = fw + n * 5408 + k0;
    const float* __restrict__ zp = zp2a + (size_t)t * 173056 + k0 * 32 + b;

    float a0 = 0.f, a1 = 0.f, a2 = 0.f, a3 = 0.f;
    for (int j = 0; j < 84; ++j) {
        a0 = fmaf(wp[0], zp[0],  a0);
        a1 = fmaf(wp[1], zp[32], a1);
        a2 = fmaf(wp[2], zp[64], a2);
        a3 = fmaf(wp[3], zp[96], a3);
        wp += 4; zp += 128;
    }
    a0 = fmaf(wp[0], zp[0],  a0);
    a1 = fmaf(wp[1], zp[32], a1);
    float a = (a0 + a1) + (a2 + a3);

    a += __shfl_down(a, 32);
    if (l < 32) part[(((size_t)t * 8 + c) * 500 + n) * 32 + l] = a;
}

// ---------------- K3b: reduce partials + bias + LIF scan over t ----------------
// grid 63, block 256; thread owns (n,b), state in regs.
__global__ __launch_bounds__(256) void k3b_lif(
    const float* __restrict__ part,  // [32t][8][500][32]
    const float* __restrict__ fb,    // [500]
    float* __restrict__ za)          // [32t][500][32]
{
    const int idx = blockIdx.x * 256 + threadIdx.x;
    if (idx >= 16000) return;
    const int n = idx >> 5;
    const float bias = fb[n];

    float v = 0.f, cu = 0.f;
    for (int t = 0; t < T_STEPS; ++t) {
        float s = 0.f;
        #pragma unroll
        for (int p = 0; p < 8; ++p)
            s += part[((size_t)t * 8 + p) * 16000 + idx];
        s += bias;

        const float vd = v + 0.1f * (cu - v);
        const float id = 0.8f * cu;
        const float z = (vd - 1.0f > 0.0f) ? 1.0f : 0.0f;
        v = (z > 0.f) ? 0.f : vd;
        cu = id + s;
        za[(size_t)t * 16000 + idx] = z;
    }
}

// ---------------- K4: readout dots per (c,t) ----------------
// grid (10 c, 32 t), block 256 = 32 b x 8 nc.
__global__ __launch_bounds__(256) void k4_dot(
    const float* __restrict__ za,   // [32t][500][32]
    const float* __restrict__ ow,   // [10,500]
    float* __restrict__ dota)       // [32t][10][32]
{
    const int c = blockIdx.x, t = blockIdx.y;
    const int tid = threadIdx.x;
    const int b = tid & 31, nc = tid >> 5;
    const float* __restrict__ wr = ow + c * 500;
    const float* __restrict__ zt = za + (size_t)t * 16000;

    float acc = 0.f;
    for (int j = 0; j < 63; ++j) {
        const int n = nc * 63 + j;
        if (n < 500) acc = fmaf(zt[n * 32 + b], wr[n], acc);
    }

    __shared__ float red[256];
    red[tid] = acc;
    __syncthreads();
    if (tid < 32) {
        float dot = 0.f;
        #pragma unroll
        for (int q = 0; q < 8; ++q) dot += red[q * 32 + tid];
        dota[((size_t)t * 10 + c) * 32 + tid] = dot;
    }
}

// ---------------- K5: LI scan + output ----------------
// 1 block, 320 threads; thread owns (c,b).
__global__ __launch_bounds__(320) void k5_li(
    const float* __restrict__ dota,  // [32t][10][32]
    float* __restrict__ outp)        // [32t][32b][10c]
{
    const int tid = threadIdx.x;
    if (tid >= 320) return;
    const int c = tid / 32, b = tid & 31;

    float vo = 0.f, io = 0.f;
    for (int t = 0; t < T_STEPS; ++t) {
        const float vout = vo + 0.1f * (io - vo);
        outp[t * 320 + b * 10 + c] = vout;
        vo = vout;
        io = 0.8f * io + dota[(t * 10 + c) * 32 + b];
    }
}

extern "C" void kernel_launch(void* const* d_in, const int* in_sizes, int n_in,
                              void* d_out, int out_size, void* d_ws, size_t ws_size,
                              hipStream_t stream) {
    const float* x  = (const float*)d_in[0];  // [32,32,1,64,64]
    const float* w1 = (const float*)d_in[1];
    const float* b1 = (const float*)d_in[2];
    const float* w2 = (const float*)d_in[3];
    const float* b2 = (const float*)d_in[4];
    const float* fw = (const float*)d_in[5];
    const float* fb = (const float*)d_in[6];
    const float* ow = (const float*)d_in[7];
    float* out = (float*)d_out;
    float* ws = (float*)d_ws;

    size_t off = 0;
    float* xT   = ws + off; off += 4194304;   // [32t][64][64][32b]
    float* zp1a = ws + off; off += 14745600;  // [32t][16*30*30][32b]
    float* zp2a = ws + off; off += 5537792;   // [32t][5408][32b]
    float* part = ws + off; off += 4096000;   // [32t][8][500][32b]
    float* za   = ws + off; off += 512000;    // [32t][500][32b]
    float* dota = ws + off; off += 10240;     // [32t][10][32b]
    // total ~29.1M floats = 116 MB; all fully written before read (no memset).

    k_tr   <<<dim3(64, 32), 256, 0, stream>>>(x, xT);
    k1_conv1<<<900, 256, 0, stream>>>(xT, w1, b1, zp1a);
    k2_conv2<<<dim3(169, 2), 256, 0, stream>>>(zp1a, w2, b2, zp2a);
    k3_fc  <<<dim3(500, 8, 32), 64, 0, stream>>>(zp2a, fw, part);
    k3b_lif<<<63, 256, 0, stream>>>(part, fb, za);
    k4_dot <<<dim3(10, 32), 256, 0, stream>>>(za, ow, dota);
    k5_li  <<<1, 320, 0, stream>>>(dota, out);
}

// Round 5
// 821.254 us; speedup vs baseline: 4.7912x; 1.4770x over previous
//
#include <hip/hip_runtime.h>

// SNN: v_dec = v + 0.1*(i - v); i_dec = 0.8*i; spike if v_dec > 1.0
// v' = spike ? 0 : v_dec; i' = i_dec + input.
// Whole-sequence kernels: LIF state lives in registers across the t-loop.

#define T_STEPS 32

// ---------------- K0: transpose x [t][b][64][64] -> xT [t][y][x][b] ----------------
__global__ __launch_bounds__(256) void k_tr(
    const float* __restrict__ x, float* __restrict__ xT)
{
    const int y = blockIdx.x, t = blockIdx.y;
    const int tid = threadIdx.x;
    __shared__ float tile[32][65];

    const int lx = tid & 63, bg = tid >> 6;
    #pragma unroll
    for (int p = 0; p < 8; ++p) {
        const int b = bg + p * 4;
        tile[b][lx] = x[((size_t)(t * 32 + b) * 64 + y) * 64 + lx];
    }
    __syncthreads();
    const int wb = tid & 31, xg = tid >> 5;
    #pragma unroll
    for (int p = 0; p < 8; ++p) {
        const int xx = xg + p * 8;
        xT[((size_t)(t * 64 + y) * 64 + xx) * 32 + wb] = tile[wb][xx];
    }
}

// ---------------- K1: conv1 (1->16) + LIF + pool, ALL timesteps ----------------
// grid 900 (pooled pos), block 256 = 32 b x 8 slots (2 co per slot).
// Window read directly from L2-cached xT; no per-t barriers.
__global__ __launch_bounds__(256) void k1_conv1(
    const float* __restrict__ xT,    // [32t,64,64,32b]
    const float* __restrict__ w1,    // [16,1,5,5]
    const float* __restrict__ b1,    // [16]
    float* __restrict__ zp1a)        // [32t][16,30,30,32b]
{
    const int pos = blockIdx.x;
    const int py = pos / 30, px = pos % 30;
    const int y0 = 2 * py, x0 = 2 * px;
    const int tid = threadIdx.x;
    const int b = tid & 31, slot = tid >> 5;

    __shared__ float ws[400];
    for (int i = tid; i < 400; i += 256) ws[i] = w1[i];
    __syncthreads();
    const float bias0 = b1[slot], bias1 = b1[slot + 8];

    float v[2][4] = {{0.f,0.f,0.f,0.f},{0.f,0.f,0.f,0.f}};
    float cu[2][4] = {{0.f,0.f,0.f,0.f},{0.f,0.f,0.f,0.f}};

    for (int t = 0; t < T_STEPS; ++t) {
        const float* __restrict__ ip =
            xT + ((size_t)(t * 64 + y0) * 64 + x0) * 32 + b;
        float xr[6][6];
        #pragma unroll
        for (int r = 0; r < 6; ++r)
            #pragma unroll
            for (int c = 0; c < 6; ++c)
                xr[r][c] = ip[(r * 64 + c) * 32];

        #pragma unroll
        for (int half = 0; half < 2; ++half) {
            const int co = slot + 8 * half;
            const float* wc = ws + co * 25;
            float a00 = 0.f, a01 = 0.f, a10 = 0.f, a11 = 0.f;
            #pragma unroll
            for (int ky = 0; ky < 5; ++ky) {
                #pragma unroll
                for (int kx = 0; kx < 5; ++kx) {
                    const float w = wc[ky * 5 + kx];
                    a00 = fmaf(w, xr[ky][kx],         a00);
                    a01 = fmaf(w, xr[ky][kx + 1],     a01);
                    a10 = fmaf(w, xr[ky + 1][kx],     a10);
                    a11 = fmaf(w, xr[ky + 1][kx + 1], a11);
                }
            }
            const float bias = half ? bias1 : bias0;
            const float inp[4] = {a00 + bias, a01 + bias, a10 + bias, a11 + bias};
            float zmax = 0.f;
            #pragma unroll
            for (int q = 0; q < 4; ++q) {
                const float vv = v[half][q], cur = cu[half][q];
                const float vd = vv + 0.1f * (cur - vv);
                const float id = 0.8f * cur;
                const float z = (vd - 1.0f > 0.0f) ? 1.0f : 0.0f;
                v[half][q] = (z > 0.f) ? 0.f : vd;
                cu[half][q] = id + inp[q];
                zmax = fmaxf(zmax, z);
            }
            zp1a[(size_t)t * 460800 + ((co * 30 + py) * 30 + px) * 32 + b] = zmax;
        }
    }
}

// ---------------- K2: conv2 (16->32)*10 + LIF + pool, ALL timesteps ----------------
// grid (169 pos, 4 co-groups of 8), block 256 = 32 b x 8 slots (1 co per slot).
__global__ __launch_bounds__(256) void k2_conv2(
    const float* __restrict__ zp1a,  // [32t][16,30,30,32b]
    const float* __restrict__ w2,    // [32,16,5,5]
    const float* __restrict__ b2,    // [32]
    float* __restrict__ zp2a)        // [32t][5408,32b]
{
    const int pos = blockIdx.x;
    const int cob = blockIdx.y * 8;
    const int py = pos / 13, px = pos % 13;
    const int y0 = 2 * py, x0 = 2 * px;
    const int tid = threadIdx.x;
    const int b = tid & 31, slot = tid >> 5;

    __shared__ float ws[3584];  // [8co][16ci][28 padded]
    __shared__ float bs[8];
    for (int i = tid; i < 3200; i += 256) {
        const int co_l = i / 400;
        const int rest = i - co_l * 400;
        const int ci = rest / 25;
        const int j = rest - ci * 25;
        ws[(co_l * 16 + ci) * 28 + j] = w2[cob * 400 + i];
    }
    if (tid < 8) bs[tid] = b2[cob + tid];
    __syncthreads();

    const int co = cob + slot;
    const float bias = bs[slot];

    float v[4] = {0.f,0.f,0.f,0.f};
    float cu[4] = {0.f,0.f,0.f,0.f};

    for (int t = 0; t < T_STEPS; ++t) {
        const float* __restrict__ zt = zp1a + (size_t)t * 460800;
        float acc[4] = {0.f, 0.f, 0.f, 0.f};

        for (int ci = 0; ci < 16; ++ci) {
            float xr[6][6];
            const float* __restrict__ ip = zt + ((ci * 30 + y0) * 30 + x0) * 32 + b;
            #pragma unroll
            for (int r = 0; r < 6; ++r)
                #pragma unroll
                for (int c = 0; c < 6; ++c)
                    xr[r][c] = ip[(r * 30 + c) * 32];

            const float* __restrict__ wA = ws + (slot * 16 + ci) * 28;
            #pragma unroll
            for (int ky = 0; ky < 5; ++ky) {
                #pragma unroll
                for (int kx = 0; kx < 5; ++kx) {
                    const float a = wA[ky * 5 + kx];
                    acc[0] = fmaf(a, xr[ky][kx],         acc[0]);
                    acc[1] = fmaf(a, xr[ky][kx + 1],     acc[1]);
                    acc[2] = fmaf(a, xr[ky + 1][kx],     acc[2]);
                    acc[3] = fmaf(a, xr[ky + 1][kx + 1], acc[3]);
                }
            }
        }

        float zmax = 0.f;
        #pragma unroll
        for (int q = 0; q < 4; ++q) {
            const float inp = 10.f * (acc[q] + bias);
            const float vv = v[q], cur = cu[q];
            const float vd = vv + 0.1f * (cur - vv);
            const float id = 0.8f * cur;
            const float z = (vd - 1.0f > 0.0f) ? 1.0f : 0.0f;
            v[q] = (z > 0.f) ? 0.f : vd;
            cu[q] = id + inp;
            zmax = fmaxf(zmax, z);
        }
        zp2a[(size_t)t * 173056 + (co * 169 + pos) * 32 + b] = zmax;
    }
}

// ---------------- K3: FC as LDS-tiled GEMM ----------------
// C[512n x 1024col] = fw[500x5408] * z[5408 x 1024], col = t*32+b.
// grid (8 ntile, 8 mtile, 8 kchunk), block 256 = 32 colgrp x 8 rowgrp.
// Each thread: 8 rows x 4 cols. K chunk 676 = 26 steps x 26.
__global__ __launch_bounds__(256) void k3_gemm(
    const float* __restrict__ zp2a,  // [32t][5408][32b]
    const float* __restrict__ fw,    // [500,5408]
    float* __restrict__ part)        // [8kc][512n][1024col]
{
    const int nt = blockIdx.x, mt = blockIdx.y, kc = blockIdx.z;
    const int tid = threadIdx.x;
    const int cx = tid & 31, ry = tid >> 5;
    const int c0 = nt * 128, m0 = mt * 64, k0 = kc * 676;

    __shared__ float A[26][64];    // [k][n]
    __shared__ float Bs[26][128];  // [k][col]

    float acc[8][4] = {};

    for (int ks = 0; ks < 26; ++ks) {
        const int kb = k0 + ks * 26;
        __syncthreads();
        for (int i = tid; i < 1664; i += 256) {
            const int row = i / 26, kk = i - row * 26;
            int n = m0 + row; if (n > 499) n = 499;  // pad rows: clamp (discarded later)
            A[kk][row] = fw[n * 5408 + kb + kk];
        }
        for (int i = tid; i < 3328; i += 256) {
            const int kk = i >> 7, c = i & 127;
            const int col = c0 + c;
            Bs[kk][c] = zp2a[(size_t)(col >> 5) * 173056 + (kb + kk) * 32 + (col & 31)];
        }
        __syncthreads();

        for (int kk = 0; kk < 26; ++kk) {
            const float4 b4 = *(const float4*)&Bs[kk][cx * 4];
            const float4 a0 = *(const float4*)&A[kk][ry * 8];
            const float4 a1 = *(const float4*)&A[kk][ry * 8 + 4];
            const float av[8] = {a0.x, a0.y, a0.z, a0.w, a1.x, a1.y, a1.z, a1.w};
            const float bv[4] = {b4.x, b4.y, b4.z, b4.w};
            #pragma unroll
            for (int i2 = 0; i2 < 8; ++i2)
                #pragma unroll
                for (int j = 0; j < 4; ++j)
                    acc[i2][j] = fmaf(av[i2], bv[j], acc[i2][j]);
        }
    }

    float* pp = part + ((size_t)kc * 512 + m0) * 1024 + c0;
    #pragma unroll
    for (int i2 = 0; i2 < 8; ++i2) {
        const int row = ry * 8 + i2;
        float4 o; o.x = acc[i2][0]; o.y = acc[i2][1]; o.z = acc[i2][2]; o.w = acc[i2][3];
        *(float4*)&pp[row * 1024 + cx * 4] = o;
    }
}

// ---------------- K3b: reduce partials + bias + LIF scan over t ----------------
// grid 63, block 256; thread owns (n,b), state in regs.
__global__ __launch_bounds__(256) void k3b_lif(
    const float* __restrict__ part,  // [8kc][512n][1024col], col = t*32+b
    const float* __restrict__ fb,    // [500]
    float* __restrict__ za)          // [32t][500][32]
{
    const int idx = blockIdx.x * 256 + threadIdx.x;
    if (idx >= 16000) return;
    const int n = idx >> 5, b = idx & 31;
    const float bias = fb[n];

    float v = 0.f, cu = 0.f;
    for (int t = 0; t < T_STEPS; ++t) {
        float s = 0.f;
        #pragma unroll
        for (int p = 0; p < 8; ++p)
            s += part[(size_t)p * 524288 + n * 1024 + t * 32 + b];
        s += bias;

        const float vd = v + 0.1f * (cu - v);
        const float id = 0.8f * cu;
        const float z = (vd - 1.0f > 0.0f) ? 1.0f : 0.0f;
        v = (z > 0.f) ? 0.f : vd;
        cu = id + s;
        za[(size_t)t * 16000 + idx] = z;
    }
}

// ---------------- K4: readout dots per (c,t) ----------------
__global__ __launch_bounds__(256) void k4_dot(
    const float* __restrict__ za,   // [32t][500][32]
    const float* __restrict__ ow,   // [10,500]
    float* __restrict__ dota)       // [32t][10][32]
{
    const int c = blockIdx.x, t = blockIdx.y;
    const int tid = threadIdx.x;
    const int b = tid & 31, nc = tid >> 5;
    const float* __restrict__ wr = ow + c * 500;
    const float* __restrict__ zt = za + (size_t)t * 16000;

    float acc = 0.f;
    for (int j = 0; j < 63; ++j) {
        const int n = nc * 63 + j;
        if (n < 500) acc = fmaf(zt[n * 32 + b], wr[n], acc);
    }

    __shared__ float red[256];
    red[tid] = acc;
    __syncthreads();
    if (tid < 32) {
        float dot = 0.f;
        #pragma unroll
        for (int q = 0; q < 8; ++q) dot += red[q * 32 + tid];
        dota[((size_t)t * 10 + c) * 32 + tid] = dot;
    }
}

// ---------------- K5: LI scan + output ----------------
__global__ __launch_bounds__(320) void k5_li(
    const float* __restrict__ dota,  // [32t][10][32]
    float* __restrict__ outp)        // [32t][32b][10c]
{
    const int tid = threadIdx.x;
    if (tid >= 320) return;
    const int c = tid / 32, b = tid & 31;

    float vo = 0.f, io = 0.f;
    for (int t = 0; t < T_STEPS; ++t) {
        const float vout = vo + 0.1f * (io - vo);
        outp[t * 320 + b * 10 + c] = vout;
        vo = vout;
        io = 0.8f * io + dota[(t * 10 + c) * 32 + b];
    }
}

extern "C" void kernel_launch(void* const* d_in, const int* in_sizes, int n_in,
                              void* d_out, int out_size, void* d_ws, size_t ws_size,
                              hipStream_t stream) {
    const float* x  = (const float*)d_in[0];  // [32,32,1,64,64]
    const float* w1 = (const float*)d_in[1];
    const float* b1 = (const float*)d_in[2];
    const float* w2 = (const float*)d_in[3];
    const float* b2 = (const float*)d_in[4];
    const float* fw = (const float*)d_in[5];
    const float* fb = (const float*)d_in[6];
    const float* ow = (const float*)d_in[7];
    float* out = (float*)d_out;
    float* ws = (float*)d_ws;

    size_t off = 0;
    float* xT   = ws + off; off += 4194304;   // [32t][64][64][32b]; dead after k1
    float* zp1a = ws + off; off += 14745600;  // [32t][16*30*30][32b]
    float* zp2a = ws + off; off += 5537792;   // [32t][5408][32b]
    float* za   = ws + off; off += 512000;    // [32t][500][32b]
    float* dota = ws + off; off += 10240;     // [32t][10][32b]
    float* part = xT;                         // alias: [8][512][1024] = 4194304 floats
    // ~100 MB total; every buffer fully written before read (no memset needed).

    k_tr    <<<dim3(64, 32), 256, 0, stream>>>(x, xT);
    k1_conv1<<<900, 256, 0, stream>>>(xT, w1, b1, zp1a);
    k2_conv2<<<dim3(169, 4), 256, 0, stream>>>(zp1a, w2, b2, zp2a);
    k3_gemm <<<dim3(8, 8, 8), 256, 0, stream>>>(zp2a, fw, part);
    k3b_lif <<<63, 256, 0, stream>>>(part, fb, za);
    k4_dot  <<<dim3(10, 32), 256, 0, stream>>>(za, ow, dota);
    k5_li   <<<1, 320, 0, stream>>>(dota, out);
}

// Round 6
// 771.505 us; speedup vs baseline: 5.1002x; 1.0645x over previous
//
#include <hip/hip_runtime.h>

// SNN: v_dec = v + 0.1*(i - v); i_dec = 0.8*i; spike if v_dec > 1.0
// v' = spike ? 0 : v_dec; i' = i_dec + input.
// Whole-sequence kernels: LIF state lives in registers across the t-loop.

#define T_STEPS 32

// Bijective XCD-chunked block swizzle (m204): XCD k gets a contiguous wgid range.
__device__ __forceinline__ int xcd_swz(int orig, int nwg) {
    const int q = nwg >> 3, r = nwg & 7;
    const int xcd = orig & 7, idx = orig >> 3;
    return (xcd < r ? xcd * (q + 1) : r * (q + 1) + (xcd - r) * q) + idx;
}

// ---------------- K0: transpose x [t][b][64][64] -> xT [t][y][x][b] ----------------
__global__ __launch_bounds__(256) void k_tr(
    const float* __restrict__ x, float* __restrict__ xT)
{
    const int y = blockIdx.x, t = blockIdx.y;
    const int tid = threadIdx.x;
    __shared__ float tile[32][65];

    const int lx = tid & 63, bg = tid >> 6;
    #pragma unroll
    for (int p = 0; p < 8; ++p) {
        const int b = bg + p * 4;
        tile[b][lx] = x[((size_t)(t * 32 + b) * 64 + y) * 64 + lx];
    }
    __syncthreads();
    const int wb = tid & 31, xg = tid >> 5;
    #pragma unroll
    for (int p = 0; p < 8; ++p) {
        const int xx = xg + p * 8;
        xT[((size_t)(t * 64 + y) * 64 + xx) * 32 + wb] = tile[wb][xx];
    }
}

// ---------------- K1: conv1 (1->16) + LIF + pool, ALL timesteps ----------------
// grid 900 (XCD-swizzled pooled pos), block 256 = 32 b x 8 slots (2 co per slot).
__global__ __launch_bounds__(256) void k1_conv1(
    const float* __restrict__ xT,    // [32t,64,64,32b]
    const float* __restrict__ w1,    // [16,1,5,5]
    const float* __restrict__ b1,    // [16]
    float* __restrict__ zp1a)        // [32t][16,30,30,32b]
{
    const int pos = xcd_swz(blockIdx.x, 900);
    const int py = pos / 30, px = pos % 30;
    const int y0 = 2 * py, x0 = 2 * px;
    const int tid = threadIdx.x;
    const int b = tid & 31, slot = tid >> 5;

    __shared__ float ws[400];
    for (int i = tid; i < 400; i += 256) ws[i] = w1[i];
    __syncthreads();
    const float bias0 = b1[slot], bias1 = b1[slot + 8];

    float v[2][4] = {{0.f,0.f,0.f,0.f},{0.f,0.f,0.f,0.f}};
    float cu[2][4] = {{0.f,0.f,0.f,0.f},{0.f,0.f,0.f,0.f}};

    for (int t = 0; t < T_STEPS; ++t) {
        float xr[6][6];
        #pragma unroll
        for (int r = 0; r < 6; ++r) {
            const float* __restrict__ ipr =
                xT + ((size_t)(t * 64 + y0 + r) * 64 + x0) * 32 + b;
            #pragma unroll
            for (int c = 0; c < 6; ++c)
                xr[r][c] = ipr[c * 32];
        }

        #pragma unroll
        for (int half = 0; half < 2; ++half) {
            const int co = slot + 8 * half;
            const float* wc = ws + co * 25;
            float a00 = 0.f, a01 = 0.f, a10 = 0.f, a11 = 0.f;
            #pragma unroll
            for (int ky = 0; ky < 5; ++ky) {
                #pragma unroll
                for (int kx = 0; kx < 5; ++kx) {
                    const float w = wc[ky * 5 + kx];
                    a00 = fmaf(w, xr[ky][kx],         a00);
                    a01 = fmaf(w, xr[ky][kx + 1],     a01);
                    a10 = fmaf(w, xr[ky + 1][kx],     a10);
                    a11 = fmaf(w, xr[ky + 1][kx + 1], a11);
                }
            }
            const float bias = half ? bias1 : bias0;
            const float inp[4] = {a00 + bias, a01 + bias, a10 + bias, a11 + bias};
            float zmax = 0.f;
            #pragma unroll
            for (int q = 0; q < 4; ++q) {
                const float vv = v[half][q], cur = cu[half][q];
                const float vd = vv + 0.1f * (cur - vv);
                const float id = 0.8f * cur;
                const float z = (vd - 1.0f > 0.0f) ? 1.0f : 0.0f;
                v[half][q] = (z > 0.f) ? 0.f : vd;
                cu[half][q] = id + inp[q];
                zmax = fmaxf(zmax, z);
            }
            zp1a[(size_t)t * 460800 + ((co * 30 + py) * 30 + px) * 32 + b] = zmax;
        }
    }
}

// ---------------- K2: conv2 (16->32)*10 + LIF + pool, ALL timesteps ----------------
// grid 676 = 169 pos x 4 co-groups (co-group MINOR in wgid), XCD-swizzled so each
// XCD owns a contiguous ~21-pos slice -> per-XCD L2 serves window + co redundancy.
// block 256 = 32 b x 8 slots (1 co per slot).
__global__ __launch_bounds__(256) void k2_conv2(
    const float* __restrict__ zp1a,  // [32t][16,30,30,32b]
    const float* __restrict__ w2,    // [32,16,5,5]
    const float* __restrict__ b2,    // [32]
    float* __restrict__ zp2a)        // [32t][5408,32b]
{
    const int wgid = xcd_swz(blockIdx.x, 676);
    const int pos = wgid >> 2;
    const int cob = (wgid & 3) * 8;
    const int py = pos / 13, px = pos % 13;
    const int y0 = 2 * py, x0 = 2 * px;
    const int tid = threadIdx.x;
    const int b = tid & 31, slot = tid >> 5;

    __shared__ float ws[3584];  // [8co][16ci][28 padded]
    __shared__ float bs[8];
    for (int i = tid; i < 3200; i += 256) {
        const int co_l = i / 400;
        const int rest = i - co_l * 400;
        const int ci = rest / 25;
        const int j = rest - ci * 25;
        ws[(co_l * 16 + ci) * 28 + j] = w2[cob * 400 + i];
    }
    if (tid < 8) bs[tid] = b2[cob + tid];
    __syncthreads();

    const int co = cob + slot;
    const float bias = bs[slot];

    float v[4] = {0.f,0.f,0.f,0.f};
    float cu[4] = {0.f,0.f,0.f,0.f};

    for (int t = 0; t < T_STEPS; ++t) {
        const float* __restrict__ zt = zp1a + (size_t)t * 460800;
        float acc[4] = {0.f, 0.f, 0.f, 0.f};

        for (int ci = 0; ci < 16; ++ci) {
            float xr[6][6];
            #pragma unroll
            for (int r = 0; r < 6; ++r) {
                const float* __restrict__ ipr =
                    zt + ((ci * 30 + y0 + r) * 30 + x0) * 32 + b;
                #pragma unroll
                for (int c = 0; c < 6; ++c)
                    xr[r][c] = ipr[c * 32];
            }

            const float* __restrict__ wA = ws + (slot * 16 + ci) * 28;
            #pragma unroll
            for (int ky = 0; ky < 5; ++ky) {
                #pragma unroll
                for (int kx = 0; kx < 5; ++kx) {
                    const float a = wA[ky * 5 + kx];
                    acc[0] = fmaf(a, xr[ky][kx],         acc[0]);
                    acc[1] = fmaf(a, xr[ky][kx + 1],     acc[1]);
                    acc[2] = fmaf(a, xr[ky + 1][kx],     acc[2]);
                    acc[3] = fmaf(a, xr[ky + 1][kx + 1], acc[3]);
                }
            }
        }

        float zmax = 0.f;
        #pragma unroll
        for (int q = 0; q < 4; ++q) {
            const float inp = 10.f * (acc[q] + bias);
            const float vv = v[q], cur = cu[q];
            const float vd = vv + 0.1f * (cur - vv);
            const float id = 0.8f * cur;
            const float z = (vd - 1.0f > 0.0f) ? 1.0f : 0.0f;
            v[q] = (z > 0.f) ? 0.f : vd;
            cu[q] = id + inp;
            zmax = fmaxf(zmax, z);
        }
        zp2a[(size_t)t * 173056 + (co * 169 + pos) * 32 + b] = zmax;
    }
}

// ---------------- K3: FC as LDS-tiled GEMM ----------------
// C[512n x 1024col] = fw[500x5408] * z[5408 x 1024], col = t*32+b.
// grid (8 ntile, 8 mtile, 8 kchunk), block 256 = 32 colgrp x 8 rowgrp.
__global__ __launch_bounds__(256) void k3_gemm(
    const float* __restrict__ zp2a,  // [32t][5408][32b]
    const float* __restrict__ fw,    // [500,5408]
    float* __restrict__ part)        // [8kc][512n][1024col]
{
    const int nt = blockIdx.x, mt = blockIdx.y, kc = blockIdx.z;
    const int tid = threadIdx.x;
    const int cx = tid & 31, ry = tid >> 5;
    const int c0 = nt * 128, m0 = mt * 64, k0 = kc * 676;

    __shared__ float A[26][64];    // [k][n]
    __shared__ float Bs[26][128];  // [k][col]

    float acc[8][4] = {};

    for (int ks = 0; ks < 26; ++ks) {
        const int kb = k0 + ks * 26;
        __syncthreads();
        for (int i = tid; i < 1664; i += 256) {
            const int row = i / 26, kk = i - row * 26;
            int n = m0 + row; if (n > 499) n = 499;  // pad rows: clamp (discarded later)
            A[kk][row] = fw[n * 5408 + kb + kk];
        }
        for (int i = tid; i < 3328; i += 256) {
            const int kk = i >> 7, c = i & 127;
            const int col = c0 + c;
            Bs[kk][c] = zp2a[(size_t)(col >> 5) * 173056 + (kb + kk) * 32 + (col & 31)];
        }
        __syncthreads();

        for (int kk = 0; kk < 26; ++kk) {
            const float4 b4 = *(const float4*)&Bs[kk][cx * 4];
            const float4 a0 = *(const float4*)&A[kk][ry * 8];
            const float4 a1 = *(const float4*)&A[kk][ry * 8 + 4];
            const float av[8] = {a0.x, a0.y, a0.z, a0.w, a1.x, a1.y, a1.z, a1.w};
            const float bv[4] = {b4.x, b4.y, b4.z, b4.w};
            #pragma unroll
            for (int i2 = 0; i2 < 8; ++i2)
                #pragma unroll
                for (int j = 0; j < 4; ++j)
                    acc[i2][j] = fmaf(av[i2], bv[j], acc[i2][j]);
        }
    }

    float* pp = part + ((size_t)kc * 512 + m0) * 1024 + c0;
    #pragma unroll
    for (int i2 = 0; i2 < 8; ++i2) {
        const int row = ry * 8 + i2;
        float4 o; o.x = acc[i2][0]; o.y = acc[i2][1]; o.z = acc[i2][2]; o.w = acc[i2][3];
        *(float4*)&pp[row * 1024 + cx * 4] = o;
    }
}

// ---------------- K3b: reduce partials + bias + LIF scan over t ----------------
__global__ __launch_bounds__(256) void k3b_lif(
    const float* __restrict__ part,  // [8kc][512n][1024col], col = t*32+b
    const float* __restrict__ fb,    // [500]
    float* __restrict__ za)          // [32t][500][32]
{
    const int idx = blockIdx.x * 256 + threadIdx.x;
    if (idx >= 16000) return;
    const int n = idx >> 5, b = idx & 31;
    const float bias = fb[n];

    float v = 0.f, cu = 0.f;
    for (int t = 0; t < T_STEPS; ++t) {
        float s = 0.f;
        #pragma unroll
        for (int p = 0; p < 8; ++p)
            s += part[(size_t)p * 524288 + n * 1024 + t * 32 + b];
        s += bias;

        const float vd = v + 0.1f * (cu - v);
        const float id = 0.8f * cu;
        const float z = (vd - 1.0f > 0.0f) ? 1.0f : 0.0f;
        v = (z > 0.f) ? 0.f : vd;
        cu = id + s;
        za[(size_t)t * 16000 + idx] = z;
    }
}

// ---------------- K4: readout dots per (c,t) ----------------
__global__ __launch_bounds__(256) void k4_dot(
    const float* __restrict__ za,   // [32t][500][32]
    const float* __restrict__ ow,   // [10,500]
    float* __restrict__ dota)       // [32t][10][32]
{
    const int c = blockIdx.x, t = blockIdx.y;
    const int tid = threadIdx.x;
    const int b = tid & 31, nc = tid >> 5;
    const float* __restrict__ wr = ow + c * 500;
    const float* __restrict__ zt = za + (size_t)t * 16000;

    float acc = 0.f;
    for (int j = 0; j < 63; ++j) {
        const int n = nc * 63 + j;
        if (n < 500) acc = fmaf(zt[n * 32 + b], wr[n], acc);
    }

    __shared__ float red[256];
    red[tid] = acc;
    __syncthreads();
    if (tid < 32) {
        float dot = 0.f;
        #pragma unroll
        for (int q = 0; q < 8; ++q) dot += red[q * 32 + tid];
        dota[((size_t)t * 10 + c) * 32 + tid] = dot;
    }
}

// ---------------- K5: LI scan + output ----------------
__global__ __launch_bounds__(320) void k5_li(
    const float* __restrict__ dota,  // [32t][10][32]
    float* __restrict__ outp)        // [32t][32b][10c]
{
    const int tid = threadIdx.x;
    if (tid >= 320) return;
    const int c = tid / 32, b = tid & 31;

    float vo = 0.f, io = 0.f;
    for (int t = 0; t < T_STEPS; ++t) {
        const float vout = vo + 0.1f * (io - vo);
        outp[t * 320 + b * 10 + c] = vout;
        vo = vout;
        io = 0.8f * io + dota[(t * 10 + c) * 32 + b];
    }
}

extern "C" void kernel_launch(void* const* d_in, const int* in_sizes, int n_in,
                              void* d_out, int out_size, void* d_ws, size_t ws_size,
                              hipStream_t stream) {
    const float* x  = (const float*)d_in[0];  // [32,32,1,64,64]
    const float* w1 = (const float*)d_in[1];
    const float* b1 = (const float*)d_in[2];
    const float* w2 = (const float*)d_in[3];
    const float* b2 = (const float*)d_in[4];
    const float* fw = (const float*)d_in[5];
    const float* fb = (const float*)d_in[6];
    const float* ow = (const float*)d_in[7];
    float* out = (float*)d_out;
    float* ws = (float*)d_ws;

    size_t off = 0;
    float* xT   = ws + off; off += 4194304;   // [32t][64][64][32b]; dead after k1
    float* zp1a = ws + off; off += 14745600;  // [32t][16*30*30][32b]
    float* zp2a = ws + off; off += 5537792;   // [32t][5408][32b]
    float* za   = ws + off; off += 512000;    // [32t][500][32b]
    float* dota = ws + off; off += 10240;     // [32t][10][32b]
    float* part = xT;                         // alias: [8][512][1024] = 4194304 floats
    // ~100 MB total; every buffer fully written before read (no memset needed).

    k_tr    <<<dim3(64, 32), 256, 0, stream>>>(x, xT);
    k1_conv1<<<900, 256, 0, stream>>>(xT, w1, b1, zp1a);
    k2_conv2<<<676, 256, 0, stream>>>(zp1a, w2, b2, zp2a);
    k3_gemm <<<dim3(8, 8, 8), 256, 0, stream>>>(zp2a, fw, part);
    k3b_lif <<<63, 256, 0, stream>>>(part, fb, za);
    k4_dot  <<<dim3(10, 32), 256, 0, stream>>>(za, ow, dota);
    k5_li   <<<1, 320, 0, stream>>>(dota, out);
}